// Round 10
// baseline (439.182 us; speedup 1.0000x reference)
//
#include <hip/hip_runtime.h>
#include <hip/hip_bf16.h>

#define NUM_CLASSES 21
#define CHANNELS 256
#define B_SZ 16
#define HF 128
#define WF 128
#define HL 512
#define WL 512
#define PIX_PER_BLOCK 512
#define TILES_PER_B (HF * WF / PIX_PER_BLOCK)   // 32
#define PCHUNK 64
#define NCHUNK (PIX_PER_BLOCK / PCHUNK)          // 8
#define FPAD 65   // word bank = (65t+p)%32 = (t+p)%32 -> exactly 2-way on reads & writes = free (m136)

__device__ __forceinline__ void load_chunk(const float* __restrict__ fb, int pbase, int t,
                                           float4* __restrict__ v) {
    #pragma unroll
    for (int i = 0; i < 16; ++i) {
        const int flat = i * 256 + t;          // float4 slot in [256ch][16 q]
        const int c = flat >> 4;
        const int q = flat & 15;
        v[i] = *(const float4*)(fb + (size_t)c * (HF * WF) + pbase + q * 4);
    }
}

// Thread t owns channel t; labels live one-per-lane so __ballot(mylbl==k) IS the
// class-k pixel bucket (scalar 64-bit mask). No per-element atomics, no branch tree.
// Grid: 16*32 = 512 blocks (2/CU via 68.6KB LDS), 256 threads.
__global__ __launch_bounds__(256) void protos_accum_kernel(
    const float* __restrict__ feats,   // [16][256][128][128]
    const int*   __restrict__ labels,  // [16][512][512]
    float* __restrict__ sums,          // [21][256] (d_ws)
    int*   __restrict__ counts)        // [21]      (d_ws)
{
    __shared__ float fbuf[CHANNELS * FPAD];   // 66,560 B, [c][p] padded
    __shared__ int   lbl[PIX_PER_BLOCK];      // 2,048 B

    const int t    = threadIdx.x;
    const int lane = t & 63;
    const int b    = blockIdx.x >> 5;
    const int tile = blockIdx.x & 31;
    const int base = tile * PIX_PER_BLOCK;

    // tile labels: 2 per thread (nearest resize: src = dst*4)
    {
        const int p0 = base + 2 * t;
        const int h0 = p0 >> 7,       w0 = p0 & 127;
        const int h1 = (p0 + 1) >> 7, w1 = (p0 + 1) & 127;
        lbl[2 * t]     = labels[(size_t)b * (HL * WL) + (size_t)(h0 * 4) * WL + w0 * 4];
        lbl[2 * t + 1] = labels[(size_t)b * (HL * WL) + (size_t)(h1 * 4) * WL + w1 * 4];
    }
    // first chunk-store barrier below also covers these lbl writes

    float acc[NUM_CLASSES];
    int   scnt[NUM_CLASSES];
    #pragma unroll
    for (int k = 0; k < NUM_CLASSES; ++k) { acc[k] = 0.0f; scnt[k] = 0; }

    const float* fb = feats + (size_t)b * CHANNELS * (HF * WF);

    float4 v[16];
    load_chunk(fb, base, t, v);                 // prefetch chunk 0

    for (int chk = 0; chk < NCHUNK; ++chk) {
        // store prefetched chunk into LDS (compiler inserts vmcnt wait)
        #pragma unroll
        for (int i = 0; i < 16; ++i) {
            const int flat = i * 256 + t;
            const int c = flat >> 4;
            const int q = flat & 15;
            float* d = &fbuf[c * FPAD + q * 4];
            d[0] = v[i].x; d[1] = v[i].y; d[2] = v[i].z; d[3] = v[i].w;
        }
        __syncthreads();

        // issue next chunk's global loads NOW; latency hides under consume
        if (chk + 1 < NCHUNK)
            load_chunk(fb, base + (chk + 1) * PCHUNK, t, v);

        // consume: ballot-bucketed, branch-tree-free
        const int mylbl = lbl[chk * PCHUNK + lane];
        const float* frow = &fbuf[t * FPAD];

        #pragma unroll
        for (int k = 0; k < NUM_CLASSES; ++k) {
            unsigned long long m = __ballot(mylbl == k);   // wave-uniform bucket mask
            scnt[k] += (int)__popcll(m);
            float s = 0.0f;
            while (m) {                                    // scalar bit-walk
                const int p = (int)__builtin_ctzll(m);
                m &= (m - 1);
                s += frow[p];                              // 2-way banked ds_read, independent per iter
            }
            acc[k] += s;
        }
        __syncthreads();   // fbuf fully consumed before next store
    }

    // flush: 21 coalesced global atomics per thread (distinct address per (k,t))
    #pragma unroll
    for (int k = 0; k < NUM_CLASSES; ++k)
        unsafeAtomicAdd(&sums[k * CHANNELS + t], acc[k]);

    // all threads hold identical scnt (ballots are wave-uniform, labels shared): one writer
    if (t == 0) {
        #pragma unroll
        for (int k = 0; k < NUM_CLASSES; ++k)
            atomicAdd(&counts[k], scnt[k]);
    }
}

// Grid: 21 blocks x 256 threads. out = [21*256 protos][21 counts]
__global__ __launch_bounds__(256) void protos_finalize_kernel(
    const float* __restrict__ sums,
    const int*   __restrict__ counts,
    float* __restrict__ out)
{
    const int k = blockIdx.x;
    const int c = threadIdx.x;
    const float cn = (float)counts[k];
    const float p = (cn > 0.0f) ? (sums[k * CHANNELS + c] / fmaxf(cn, 1.0f)) : 0.0f;
    out[k * CHANNELS + c] = p;
    if (c == 0) out[NUM_CLASSES * CHANNELS + k] = cn;
}

extern "C" void kernel_launch(void* const* d_in, const int* in_sizes, int n_in,
                              void* d_out, int out_size, void* d_ws, size_t ws_size,
                              hipStream_t stream) {
    const float* feats  = (const float*)d_in[0];
    const int*   labels = (const int*)d_in[1];
    float* sums   = (float*)d_ws;                          // [21*256]
    int*   counts = (int*)(sums + NUM_CLASSES * CHANNELS); // [21]
    float* out    = (float*)d_out;

    hipMemsetAsync(d_ws, 0,
                   (NUM_CLASSES * CHANNELS) * sizeof(float) + NUM_CLASSES * sizeof(int),
                   stream);

    dim3 grid(B_SZ * TILES_PER_B);   // 512
    dim3 block(256);
    protos_accum_kernel<<<grid, block, 0, stream>>>(feats, labels, sums, counts);

    protos_finalize_kernel<<<dim3(NUM_CLASSES), dim3(CHANNELS), 0, stream>>>(sums, counts, out);
}

// Round 11
// 406.035 us; speedup vs baseline: 1.0816x; 1.0816x over previous
//
#include <hip/hip_runtime.h>
#include <hip/hip_bf16.h>

#define NUM_CLASSES 21
#define CHANNELS 256
#define B_SZ 16
#define HW 16384            // 128*128 feature pixels
#define HL 512
#define WL 512
#define CH_PER_BLOCK 64     // one wave-quad group covers 16 ch; 4 waves = 64 ch
#define PIXTILE 1024
#define N_CG (CHANNELS / CH_PER_BLOCK)   // 4
#define N_PT (HW / PIXTILE)              // 16

// Dense predicated accumulation: per element, 21 statically-unrolled
// cmp+cndmask+add (63 VALU ops) -- no scalar dispatch, no runtime-trip loops,
// no LDS for features. Quad of lanes (t&3) shares channel c = c0 + (t>>2):
// 4 consecutive float4 = 64B coalesced per quad.
// Grid: 16 B x 4 chgrp x 16 pixtile = 1024 blocks, 256 threads.
__global__ __launch_bounds__(256) void protos_accum_kernel(
    const float* __restrict__ feats,   // [16][256][128][128]
    const int*   __restrict__ labels,  // [16][512][512]
    float* __restrict__ sums,          // [21][256] (d_ws)
    int*   __restrict__ counts)        // [21]      (d_ws)
{
    __shared__ int lbl[PIXTILE];       // 4 KB
    __shared__ int cnt[NUM_CLASSES];

    const int t   = threadIdx.x;
    const int bid = blockIdx.x;
    const int b   = bid >> 6;          // / (N_CG*N_PT)
    const int cg  = (bid >> 4) & 3;
    const int pt  = bid & 15;
    const int c0  = cg * CH_PER_BLOCK;
    const int P0  = pt * PIXTILE;

    if (t < NUM_CLASSES) cnt[t] = 0;

    // stage labels for this pixel tile: thread t -> pixels P0+4t .. 4t+3
    // nearest resize: src = (h*4, w*4)
    int4 l4s;
    {
        const int p = P0 + 4 * t;
        #pragma unroll
        for (int e = 0; e < 4; ++e) {
            const int pp = p + e;
            const int h = pp >> 7, w = pp & 127;
            ((int*)&l4s)[e] = labels[(size_t)b * (HL * WL) + (size_t)(h * 4) * WL + w * 4];
        }
        *(int4*)&lbl[4 * t] = l4s;
    }
    __syncthreads();

    // counts: only cg==0 blocks count (labels identical across channel groups)
    if (cg == 0) {
        atomicAdd(&cnt[l4s.x], 1);   // native ds_add_u32, ~49-deep avg: negligible
        atomicAdd(&cnt[l4s.y], 1);
        atomicAdd(&cnt[l4s.z], 1);
        atomicAdd(&cnt[l4s.w], 1);
    }

    float acc[NUM_CLASSES];
    #pragma unroll
    for (int k = 0; k < NUM_CLASSES; ++k) acc[k] = 0.0f;

    const int c = c0 + (t >> 2);
    const int q = t & 3;
    const float* fb = feats + (size_t)b * CHANNELS * HW + (size_t)c * HW + P0;

    #pragma unroll 2
    for (int i = 0; i < PIXTILE / 16; ++i) {      // 64 iters; quad covers 16 px/iter
        const int poff = i * 16 + q * 4;          // this lane's float4 pixel offset
        const float4 f  = *(const float4*)(fb + poff);
        const int4   l4 = *(const int4*)&lbl[poff];

        #pragma unroll
        for (int e = 0; e < 4; ++e) {
            const float v  = (e == 0) ? f.x : (e == 1) ? f.y : (e == 2) ? f.z : f.w;
            const int  lab = (e == 0) ? l4.x : (e == 1) ? l4.y : (e == 2) ? l4.z : l4.w;
            #pragma unroll
            for (int k = 0; k < NUM_CLASSES; ++k)
                acc[k] += (lab == k) ? v : 0.0f;   // v_cmp + v_cndmask + v_add
        }
    }

    // merge quad partials (lanes sharing a channel), flush one atomic per (k,c)
    #pragma unroll
    for (int k = 0; k < NUM_CLASSES; ++k) {
        float s = acc[k];
        s += __shfl_xor(s, 1);
        s += __shfl_xor(s, 2);
        if (q == 0) unsafeAtomicAdd(&sums[k * CHANNELS + c], s);
    }

    __syncthreads();
    if (cg == 0 && t < NUM_CLASSES) atomicAdd(&counts[t], cnt[t]);
}

// Grid: 21 blocks x 256 threads. out = [21*256 protos][21 counts]
__global__ __launch_bounds__(256) void protos_finalize_kernel(
    const float* __restrict__ sums,
    const int*   __restrict__ counts,
    float* __restrict__ out)
{
    const int k = blockIdx.x;
    const int c = threadIdx.x;
    const float cn = (float)counts[k];
    const float p = (cn > 0.0f) ? (sums[k * CHANNELS + c] / fmaxf(cn, 1.0f)) : 0.0f;
    out[k * CHANNELS + c] = p;
    if (c == 0) out[NUM_CLASSES * CHANNELS + k] = cn;
}

extern "C" void kernel_launch(void* const* d_in, const int* in_sizes, int n_in,
                              void* d_out, int out_size, void* d_ws, size_t ws_size,
                              hipStream_t stream) {
    const float* feats  = (const float*)d_in[0];
    const int*   labels = (const int*)d_in[1];
    float* sums   = (float*)d_ws;                          // [21*256]
    int*   counts = (int*)(sums + NUM_CLASSES * CHANNELS); // [21]
    float* out    = (float*)d_out;

    hipMemsetAsync(d_ws, 0,
                   (NUM_CLASSES * CHANNELS) * sizeof(float) + NUM_CLASSES * sizeof(int),
                   stream);

    dim3 grid(B_SZ * N_CG * N_PT);   // 1024
    dim3 block(256);
    protos_accum_kernel<<<grid, block, 0, stream>>>(feats, labels, sums, counts);

    protos_finalize_kernel<<<dim3(NUM_CLASSES), dim3(CHANNELS), 0, stream>>>(sums, counts, out);
}